// Round 19
// baseline (162.037 us; speedup 1.0000x reference)
//
#include <hip/hip_runtime.h>
#include <hip/hip_bf16.h>

#define BATCH   2048
#define NPAR    256
#define NF      32
#define NG      16
#define NBR     4
#define OFS     262144
#define DOUT    128
#define NROWSX  (OFS + NPAR*BATCH)     // 786432 rows of x
#define MROWS   (NPAR*BATCH)           // 524288 parent rows
#define CHBASE  (NROWSX*NF)            // float offset of children region in out
#define NMLP    4096                   // MLP blocks: 8 waves x 1 tile each
#define NCOPY   2048                   // copy blocks
#define CPN4    (NROWSX*NF/4)          // 6291456 float4 to copy

typedef short bf16x8 __attribute__((ext_vector_type(8)));   // 8 bf16 bit-patterns
typedef float f32x4  __attribute__((ext_vector_type(4)));

// ws layout (bytes): [0,1MB) G1 f32 | +32KB W2frag | +8KB W1frag
#define WSOFF_W2F  1048576
#define WSOFF_W1F  (1048576 + 32768)

__device__ __forceinline__ unsigned short f2bf(float f){
  unsigned int u = __float_as_uint(f);
  u += 0x7FFFu + ((u >> 16) & 1u);          // RNE
  return (unsigned short)(u >> 16);
}

// blocks [0,128): G1[e][j] = b1[j] + sum_k global[e][k]*W1[32+k][j], 8x strided
// blocks [128,138): pack W2 (sigma, t<2048) / W1-feature-half (t in [2048,2560)).
// sigma(8g+e) = (e<4 ? 4g+e : 16+4g+e-4) lets GEMM2's A-operand be a direct
// register repack of acc1 (no LDS round-trip); MFMA is invariant when both
// operands share the k permutation.
__global__ void k_prep(const float* __restrict__ gf, const float* __restrict__ W1,
                       const float* __restrict__ b1, const float* __restrict__ W2,
                       char* __restrict__ ws){
  int bid = blockIdx.x, tid = threadIdx.x;
  if (bid < 128){
    for (int idx = bid*256 + tid; idx < BATCH*DOUT; idx += 128*256){
      int e = idx >> 7, j = idx & 127;
      float s = b1[j];
      const float* grow = gf + e*NG;
      const float* w = W1 + NF*DOUT + j;
      #pragma unroll
      for (int k = 0; k < NG; k++) s = fmaf(grow[k], w[k*DOUT], s);
      ((float*)ws)[idx] = s;
    }
    return;
  }
  int t = (bid - 128)*256 + tid;           // 0..2559
  if (t < 2048){
    // W2 fragment uint4 t: f = t>>6 (kk*8+n), lane l = t&63
    int f = t >> 6, l = t & 63;
    int kk = f >> 3, n = f & 7;
    int g4  = 4*(l >> 4);
    int col = 16*n + (l & 15);
    union { uint4 q; unsigned short u[8]; } w;
    #pragma unroll
    for (int e = 0; e < 8; e++){
      int krow = 32*kk + (e < 4 ? g4 + e : 16 + g4 + (e - 4));   // sigma
      w.u[e] = f2bf(W2[krow*DOUT + col]);
    }
    ((uint4*)(ws + WSOFF_W2F))[t] = w.q;
  } else {
    int q = t - 2048;                      // 0..511: W1 feature-half fragments
    int n = q >> 6, l = q & 63;
    int kb = 8*(l >> 4);
    int col = 16*n + (l & 15);
    union { uint4 v; unsigned short u[8]; } w;
    #pragma unroll
    for (int e = 0; e < 8; e++) w.u[e] = f2bf(W1[(kb + e)*DOUT + col]);
    ((uint4*)(ws + WSOFF_W1F))[q] = w.v;
  }
}

// Main kernel, 512 threads, NO occupancy hints. 40 KB LDS -> 4 blocks/CU.
// bid%3==2 -> pure copy block; else MLP block (8 waves x 1 tile each).
// Residual via f32 scalars from the x row line (L1-hot), not R-MFMA.
__global__ void k_main(
    const float* __restrict__ x, const int* __restrict__ pidx,
    const float* __restrict__ b2, const char* __restrict__ ws,
    float* __restrict__ out)
{
  __shared__ uint4 sB2[2048];   // 32 KB: W2 B-fragments [frag(kk*8+n)][lane]
  __shared__ uint4 sW1[512];    //  8 KB: W1 B-fragments [frag n][lane]

  const int bid = blockIdx.x;
  const int tid = threadIdx.x;

  if (bid % 3 == 2){
    // ---- copy path: out[0:NROWSX*NF] = x, pure bandwidth, free-running ----
    const int cid = bid / 3;                      // 0..NCOPY-1
    const float4* src4 = (const float4*)x;
    float4* dst4 = (float4*)out;
    for (int i = cid*512 + tid; i < CPN4; i += NCOPY*512)
      dst4[i] = src4[i];
    return;
  }
  const int mid = (bid/3)*2 + (bid % 3);          // 0..NMLP-1

  // ---- stage pre-packed fragments into LDS (5 x 16B per thread) ----
  const uint4* W2f = (const uint4*)(ws + WSOFF_W2F);
  const uint4* W1f = (const uint4*)(ws + WSOFF_W1F);
  #pragma unroll
  for (int i = 0; i < 4; i++) sB2[i*512 + tid] = W2f[i*512 + tid];
  sW1[tid & 511] = W1f[tid & 511];
  __syncthreads();

  const int lane = tid & 63;
  const int wv   = tid >> 6;
  const int r15  = lane & 15;
  const int g    = lane >> 4;
  const float* G1 = (const float*)ws;

  const bf16x8* B2f = (const bf16x8*)sB2;
  const bf16x8* B1f = (const bf16x8*)sW1;          // frags 0..7

  const int tl   = mid*8 + wv;             // tile index (one per wave)
  const int row0 = tl*16;

  // This lane's batch row within the tile is r15 (transposed layout).
  const int idxA = pidx[row0 + r15];

  // x row: A/B fragment source (cols 8g..8g+7)
  const float* ap = x + idxA*NF + 8*g;
  float4 a0 = *(const float4*)ap;
  float4 a1 = *(const float4*)(ap + 4);

  // residual scalars x[idxA][4n+g] — same 128B line as a0/a1 (L1-hot);
  // issued now, consumed only in the epilogue.
  float xres[8];
  #pragma unroll
  for (int n = 0; n < 8; n++) xres[n] = x[idxA*NF + 4*n + g];

  // GEMM1 acc init: G1 row (bias + global half folded in), float4 loads
  const int g1r = idxA & (BATCH-1);
  f32x4 acc1[8];
  #pragma unroll
  for (int n = 0; n < 8; n++)
    acc1[n] = *(const f32x4*)(G1 + g1r*DOUT + 16*n + 4*g);

  // convert A-fragment
  union { bf16x8 v; __hip_bfloat162 h[4]; } af;
  af.h[0] = __float22bfloat162_rn(make_float2(a0.x, a0.y));
  af.h[1] = __float22bfloat162_rn(make_float2(a0.z, a0.w));
  af.h[2] = __float22bfloat162_rn(make_float2(a1.x, a1.y));
  af.h[3] = __float22bfloat162_rn(make_float2(a1.z, a1.w));

  // GEMM1 (transposed): acc1[n][r] = h1[row_r15][16n+4g+r]
  #pragma unroll
  for (int n = 0; n < 8; n++)
    acc1[n] = __builtin_amdgcn_mfma_f32_16x16x32_bf16(B1f[n*64 + lane], af.v, acc1[n], 0, 0, 0);

  // leaky-relu + pack to bf16 pairs, all in registers
  __hip_bfloat162 pa[8][2];
  #pragma unroll
  for (int n = 0; n < 8; n++){
    float v0 = acc1[n][0], v1 = acc1[n][1], v2 = acc1[n][2], v3 = acc1[n][3];
    v0 = v0 > 0.f ? v0 : 0.01f*v0;
    v1 = v1 > 0.f ? v1 : 0.01f*v1;
    v2 = v2 > 0.f ? v2 : 0.01f*v2;
    v3 = v3 > 0.f ? v3 : 0.01f*v3;
    pa[n][0] = __float22bfloat162_rn(make_float2(v0, v1));
    pa[n][1] = __float22bfloat162_rn(make_float2(v2, v3));
  }

  // GEMM2: b2 folded into acc init. A-operand for MFMA kk =
  // {acc1[2kk], acc1[2kk+1]} packed — sigma in the W2 fragments makes
  // this exact (no LDS round-trip for h1).
  f32x4 acc2[8];
  #pragma unroll
  for (int n = 0; n < 8; n++)
    acc2[n] = *(const f32x4*)(b2 + 16*n + 4*g);
  #pragma unroll
  for (int kk = 0; kk < 4; kk++){
    union { bf16x8 v; __hip_bfloat162 h[4]; } a2;
    a2.h[0] = pa[2*kk][0];   a2.h[1] = pa[2*kk][1];
    a2.h[2] = pa[2*kk+1][0]; a2.h[3] = pa[2*kk+1][1];
    #pragma unroll
    for (int n = 0; n < 8; n++)
      acc2[n] = __builtin_amdgcn_mfma_f32_16x16x32_bf16(B2f[(kk*8 + n)*64 + lane], a2.v, acc2[n], 0, 0, 0);
  }

  // epilogue: + broadcast residual (same scalar over 4 cols), f32x4 store
  const int p  = row0 >> 11;               // parent (tiles never cross parents)
  const int b0 = row0 & (BATCH-1);
  const int orow = CHBASE + ((p*NBR)*BATCH + b0 + r15)*NF;
  #pragma unroll
  for (int n = 0; n < 8; n++){
    int c0 = 16*n + 4*g;                   // first of 4 consecutive output cols
    int br = c0 >> 5, fc0 = c0 & 31;
    f32x4 v = acc2[n];
    float rsd = xres[n];
    v[0] += rsd; v[1] += rsd; v[2] += rsd; v[3] += rsd;
    *(f32x4*)(out + orow + br*(BATCH*NF) + fc0) = v;
  }
}

extern "C" void kernel_launch(void* const* d_in, const int* in_sizes, int n_in,
                              void* d_out, int out_size, void* d_ws, size_t ws_size,
                              hipStream_t stream){
  const float* x   = (const float*)d_in[0];
  const float* gf  = (const float*)d_in[1];
  const int*   pidx= (const int*)d_in[2];
  const float* W1  = (const float*)d_in[3];
  const float* b1  = (const float*)d_in[4];
  const float* W2  = (const float*)d_in[5];
  const float* b2  = (const float*)d_in[6];
  float* out = (float*)d_out;
  char* ws   = (char*)d_ws;               // 1MB G1 + 40KB packed fragments

  k_prep<<<138, 256, 0, stream>>>(gf, W1, b1, W2, ws);
  k_main<<<NMLP + NCOPY, 512, 0, stream>>>(x, pidx, b2, ws, out);
}

// Round 20
// 151.472 us; speedup vs baseline: 1.0697x; 1.0697x over previous
//
#include <hip/hip_runtime.h>
#include <hip/hip_bf16.h>

#define BATCH   2048
#define NPAR    256
#define NF      32
#define NG      16
#define NBR     4
#define OFS     262144
#define DOUT    128
#define NROWSX  (OFS + NPAR*BATCH)     // 786432 rows of x
#define MROWS   (NPAR*BATCH)           // 524288 parent rows
#define CHBASE  (NROWSX*NF)            // float offset of children region in out
#define NMLP    4096                   // MLP blocks: 8 waves x 1 tile each
#define NCOPY   1024                   // copy blocks (non-parent region only)
#define CPNP4   (OFS*NF/4)             // 2097152 float4 in rows [0, OFS)

typedef short bf16x8 __attribute__((ext_vector_type(8)));   // 8 bf16 bit-patterns
typedef float f32x4  __attribute__((ext_vector_type(4)));

// ws layout (bytes): [0,1MB) G1 f32 | +32KB W2frag | +8KB W1frag | +8KB Rfrag
#define WSOFF_W2F  1048576
#define WSOFF_W1F  (1048576 + 32768)
#define WSOFF_RF   (1048576 + 32768 + 8192)

__device__ __forceinline__ unsigned short f2bf(float f){
  unsigned int u = __float_as_uint(f);
  u += 0x7FFFu + ((u >> 16) & 1u);          // RNE
  return (unsigned short)(u >> 16);
}

// blocks [0,128): G1[e][j] = b1[j] + sum_k global[e][k]*W1[32+k][j], 8x strided
// blocks [128,140): pack W2 (sigma, t<2048) / W1 (t in [2048,2560)) /
// R fragments (t in [2560,3072)). Grid MUST be 140 so t reaches 3071.
// sigma(8g+e) = (e<4 ? 4g+e : 16+4g+e-4) lets GEMM2's A-operand be a direct
// register repack of acc1 (no LDS round-trip); MFMA is invariant when both
// operands share the k permutation.
__global__ void k_prep(const float* __restrict__ gf, const float* __restrict__ W1,
                       const float* __restrict__ b1, const float* __restrict__ W2,
                       char* __restrict__ ws){
  int bid = blockIdx.x, tid = threadIdx.x;
  if (bid < 128){
    for (int idx = bid*256 + tid; idx < BATCH*DOUT; idx += 128*256){
      int e = idx >> 7, j = idx & 127;
      float s = b1[j];
      const float* grow = gf + e*NG;
      const float* w = W1 + NF*DOUT + j;
      #pragma unroll
      for (int k = 0; k < NG; k++) s = fmaf(grow[k], w[k*DOUT], s);
      ((float*)ws)[idx] = s;
    }
    return;
  }
  int t = (bid - 128)*256 + tid;           // 0..3071
  if (t < 2048){
    // W2 fragment uint4 t: f = t>>6 (kk*8+n), lane l = t&63
    int f = t >> 6, l = t & 63;
    int kk = f >> 3, n = f & 7;
    int g4  = 4*(l >> 4);
    int col = 16*n + (l & 15);
    union { uint4 q; unsigned short u[8]; } w;
    #pragma unroll
    for (int e = 0; e < 8; e++){
      int krow = 32*kk + (e < 4 ? g4 + e : 16 + g4 + (e - 4));   // sigma
      w.u[e] = f2bf(W2[krow*DOUT + col]);
    }
    ((uint4*)(ws + WSOFF_W2F))[t] = w.q;
  } else if (t < 2560){
    int q = t - 2048;                      // 0..511: W1 feature-half fragments
    int n = q >> 6, l = q & 63;
    int kb = 8*(l >> 4);
    int col = 16*n + (l & 15);
    union { uint4 v; unsigned short u[8]; } w;
    #pragma unroll
    for (int e = 0; e < 8; e++) w.u[e] = f2bf(W1[(kb + e)*DOUT + col]);
    ((uint4*)(ws + WSOFF_W1F))[q] = w.v;
  } else {
    // R fragments: A[r][k] = 1 iff k == 4n + (r>>2)  (repeat_interleave matrix)
    int q2 = t - 2560;                     // 0..511
    int n = q2 >> 6, l = q2 & 63;
    int g = l >> 4, r = l & 15;
    int e1 = 4*n + (r >> 2) - 8*g;
    union { uint4 v; unsigned short u[8]; } w;
    #pragma unroll
    for (int e = 0; e < 8; e++) w.u[e] = (e == e1) ? 0x3F80 : 0;
    ((uint4*)(ws + WSOFF_RF))[q2] = w.v;
  }
}

// Main kernel, 512 threads, NO occupancy hints. 48 KB LDS -> 3 blocks/CU.
// Grid = NMLP + NCOPY = 5120. bid%5==4 -> copy block for rows [0,OFS) only
// (the parent-region copy is emitted by the MLP blocks from their gathered
// registers — saves re-reading 64 MB); else MLP (8 waves x 1 tile).
__global__ void k_main(
    const float* __restrict__ x, const int* __restrict__ pidx,
    const float* __restrict__ b2, const char* __restrict__ ws,
    float* __restrict__ out)
{
  __shared__ uint4 sB2[2048];   // 32 KB: W2 B-fragments [frag(kk*8+n)][lane]
  __shared__ uint4 sWR[1024];   // 16 KB: [0,512) W1 frags, [512,1024) R frags

  const int bid = blockIdx.x;
  const int tid = threadIdx.x;

  if (bid % 5 == 4){
    // ---- copy path: out[0:OFS*NF] = x[0:OFS*NF] (non-parent rows) ----
    const int cid = bid / 5;                      // 0..NCOPY-1
    const float4* src4 = (const float4*)x;
    float4* dst4 = (float4*)out;
    for (int i = cid*512 + tid; i < CPNP4; i += NCOPY*512)
      dst4[i] = src4[i];
    return;
  }
  const int mid = (bid/5)*4 + (bid % 5);          // 0..NMLP-1

  // ---- stage pre-packed fragments into LDS (6 x 16B per thread) ----
  const uint4* W2f = (const uint4*)(ws + WSOFF_W2F);
  const uint4* WRf = (const uint4*)(ws + WSOFF_W1F);  // W1+R contiguous, 1024
  #pragma unroll
  for (int i = 0; i < 4; i++) sB2[i*512 + tid] = W2f[i*512 + tid];
  sWR[tid] = WRf[tid];                   // W1 fragments
  sWR[512 + tid] = WRf[512 + tid];       // R fragments
  __syncthreads();

  const int lane = tid & 63;
  const int wv   = tid >> 6;
  const int r15  = lane & 15;
  const int g    = lane >> 4;
  const float* G1 = (const float*)ws;

  const bf16x8* B2f = (const bf16x8*)sB2;
  const bf16x8* B1f = (const bf16x8*)sWR;          // frags 0..7
  const bf16x8* Rf  = (const bf16x8*)(sWR + 512);  // frags 0..7

  const int tl   = mid*8 + wv;             // tile index (one per wave)
  const int row0 = tl*16;

  // This lane's batch row within the tile is r15 (transposed layout).
  const int idxA = pidx[row0 + r15];

  // x row: A/B fragment source (cols 8g..8g+7)
  const float* ap = x + idxA*NF + 8*g;
  float4 a0 = *(const float4*)ap;
  float4 a1 = *(const float4*)(ap + 4);

  // Parent-region copy from the gathered registers: the wave's 4 g-lanes
  // of each row hold the full 128B line; rows are contiguous (pidx covers
  // [OFS, NROWSX)). Independent stores, issue early, fill the store pipe.
  {
    float4* pc = (float4*)(out + idxA*NF + 8*g);
    pc[0] = a0;
    pc[1] = a1;
  }

  // GEMM1 acc init: G1 row (bias + global half folded in), float4 loads
  const int g1r = idxA & (BATCH-1);
  f32x4 acc1[8];
  #pragma unroll
  for (int n = 0; n < 8; n++)
    acc1[n] = *(const f32x4*)(G1 + g1r*DOUT + 16*n + 4*g);

  // convert A-fragment
  union { bf16x8 v; __hip_bfloat162 h[4]; } af;
  af.h[0] = __float22bfloat162_rn(make_float2(a0.x, a0.y));
  af.h[1] = __float22bfloat162_rn(make_float2(a0.z, a0.w));
  af.h[2] = __float22bfloat162_rn(make_float2(a1.x, a1.y));
  af.h[3] = __float22bfloat162_rn(make_float2(a1.z, a1.w));

  // GEMM1 (transposed): acc1[n][r] = h1[row_r15][16n+4g+r]
  #pragma unroll
  for (int n = 0; n < 8; n++)
    acc1[n] = __builtin_amdgcn_mfma_f32_16x16x32_bf16(B1f[n*64 + lane], af.v, acc1[n], 0, 0, 0);

  // leaky-relu + pack to bf16 pairs, all in registers
  __hip_bfloat162 pa[8][2];
  #pragma unroll
  for (int n = 0; n < 8; n++){
    float v0 = acc1[n][0], v1 = acc1[n][1], v2 = acc1[n][2], v3 = acc1[n][3];
    v0 = v0 > 0.f ? v0 : 0.01f*v0;
    v1 = v1 > 0.f ? v1 : 0.01f*v1;
    v2 = v2 > 0.f ? v2 : 0.01f*v2;
    v3 = v3 > 0.f ? v3 : 0.01f*v3;
    pa[n][0] = __float22bfloat162_rn(make_float2(v0, v1));
    pa[n][1] = __float22bfloat162_rn(make_float2(v2, v3));
  }

  // GEMM2: b2 folded into init, residual folded in via R-fragment MFMA.
  // A-operand for MFMA kk = {acc1[2kk], acc1[2kk+1]} packed — the sigma
  // permutation baked into the W2 fragments makes this exact (no LDS).
  f32x4 acc2[8];
  #pragma unroll
  for (int n = 0; n < 8; n++)
    acc2[n] = *(const f32x4*)(b2 + 16*n + 4*g);
  #pragma unroll
  for (int n = 0; n < 8; n++)
    acc2[n] = __builtin_amdgcn_mfma_f32_16x16x32_bf16(Rf[n*64 + lane], af.v, acc2[n], 0, 0, 0);
  #pragma unroll
  for (int kk = 0; kk < 4; kk++){
    union { bf16x8 v; __hip_bfloat162 h[4]; } a2;
    a2.h[0] = pa[2*kk][0];   a2.h[1] = pa[2*kk][1];
    a2.h[2] = pa[2*kk+1][0]; a2.h[3] = pa[2*kk+1][1];
    #pragma unroll
    for (int n = 0; n < 8; n++)
      acc2[n] = __builtin_amdgcn_mfma_f32_16x16x32_bf16(B2f[(kk*8 + n)*64 + lane], a2.v, acc2[n], 0, 0, 0);
  }

  // epilogue: pure f32x4 stores to children layout (no trailing loads)
  const int p  = row0 >> 11;               // parent (tiles never cross parents)
  const int b0 = row0 & (BATCH-1);
  const int orow = CHBASE + ((p*NBR)*BATCH + b0 + r15)*NF;
  #pragma unroll
  for (int n = 0; n < 8; n++){
    int c0 = 16*n + 4*g;                   // first of 4 consecutive output cols
    int br = c0 >> 5, fc0 = c0 & 31;
    *(f32x4*)(out + orow + br*(BATCH*NF) + fc0) = acc2[n];
  }
}

extern "C" void kernel_launch(void* const* d_in, const int* in_sizes, int n_in,
                              void* d_out, int out_size, void* d_ws, size_t ws_size,
                              hipStream_t stream){
  const float* x   = (const float*)d_in[0];
  const float* gf  = (const float*)d_in[1];
  const int*   pidx= (const int*)d_in[2];
  const float* W1  = (const float*)d_in[3];
  const float* b1  = (const float*)d_in[4];
  const float* W2  = (const float*)d_in[5];
  const float* b2  = (const float*)d_in[6];
  float* out = (float*)d_out;
  char* ws   = (char*)d_ws;               // 1MB G1 + 48KB packed fragments

  k_prep<<<140, 256, 0, stream>>>(gf, W1, b1, W2, ws);
  k_main<<<NMLP + NCOPY, 512, 0, stream>>>(x, pidx, b2, ws, out);
}

// Round 21
// 148.163 us; speedup vs baseline: 1.0936x; 1.0223x over previous
//
#include <hip/hip_runtime.h>
#include <hip/hip_bf16.h>

#define BATCH   2048
#define NPAR    256
#define NF      32
#define NG      16
#define NBR     4
#define OFS     262144
#define DOUT    128
#define NROWSX  (OFS + NPAR*BATCH)     // 786432 rows of x
#define MROWS   (NPAR*BATCH)           // 524288 parent rows
#define CHBASE  (NROWSX*NF)            // float offset of children region in out
#define NMLP    4096                   // all blocks: 8 waves x 1 tile + copy slice
#define CPN4    (NROWSX*NF/4)          // 6291456 = 3 * 4096 * 512 exactly

typedef short bf16x8 __attribute__((ext_vector_type(8)));   // 8 bf16 bit-patterns
typedef float f32x4  __attribute__((ext_vector_type(4)));

// ws layout (bytes): [0,1MB) G1 f32 | +32KB W2frag | +8KB W1frag | +8KB Rfrag
#define WSOFF_W2F  1048576
#define WSOFF_W1F  (1048576 + 32768)
#define WSOFF_RF   (1048576 + 32768 + 8192)

__device__ __forceinline__ unsigned short f2bf(float f){
  unsigned int u = __float_as_uint(f);
  u += 0x7FFFu + ((u >> 16) & 1u);          // RNE
  return (unsigned short)(u >> 16);
}

// blocks [0,128): G1[e][j] = b1[j] + sum_k global[e][k]*W1[32+k][j], 8x strided
// blocks [128,140): pack W2 (sigma, t<2048) / W1 (t in [2048,2560)) /
// R fragments (t in [2560,3072)). Grid MUST be 140 so t reaches 3071.
// sigma(8g+e) = (e<4 ? 4g+e : 16+4g+e-4) lets GEMM2's A-operand be a direct
// register repack of acc1 (no LDS round-trip); MFMA is invariant when both
// operands share the k permutation.
__global__ void k_prep(const float* __restrict__ gf, const float* __restrict__ W1,
                       const float* __restrict__ b1, const float* __restrict__ W2,
                       char* __restrict__ ws){
  int bid = blockIdx.x, tid = threadIdx.x;
  if (bid < 128){
    for (int idx = bid*256 + tid; idx < BATCH*DOUT; idx += 128*256){
      int e = idx >> 7, j = idx & 127;
      float s = b1[j];
      const float* grow = gf + e*NG;
      const float* w = W1 + NF*DOUT + j;
      #pragma unroll
      for (int k = 0; k < NG; k++) s = fmaf(grow[k], w[k*DOUT], s);
      ((float*)ws)[idx] = s;
    }
    return;
  }
  int t = (bid - 128)*256 + tid;           // 0..3071
  if (t < 2048){
    // W2 fragment uint4 t: f = t>>6 (kk*8+n), lane l = t&63
    int f = t >> 6, l = t & 63;
    int kk = f >> 3, n = f & 7;
    int g4  = 4*(l >> 4);
    int col = 16*n + (l & 15);
    union { uint4 q; unsigned short u[8]; } w;
    #pragma unroll
    for (int e = 0; e < 8; e++){
      int krow = 32*kk + (e < 4 ? g4 + e : 16 + g4 + (e - 4));   // sigma
      w.u[e] = f2bf(W2[krow*DOUT + col]);
    }
    ((uint4*)(ws + WSOFF_W2F))[t] = w.q;
  } else if (t < 2560){
    int q = t - 2048;                      // 0..511: W1 feature-half fragments
    int n = q >> 6, l = q & 63;
    int kb = 8*(l >> 4);
    int col = 16*n + (l & 15);
    union { uint4 v; unsigned short u[8]; } w;
    #pragma unroll
    for (int e = 0; e < 8; e++) w.u[e] = f2bf(W1[(kb + e)*DOUT + col]);
    ((uint4*)(ws + WSOFF_W1F))[q] = w.v;
  } else {
    // R fragments: A[r][k] = 1 iff k == 4n + (r>>2)  (repeat_interleave matrix)
    int q2 = t - 2560;                     // 0..511
    int n = q2 >> 6, l = q2 & 63;
    int g = l >> 4, r = l & 15;
    int e1 = 4*n + (r >> 2) - 8*g;
    union { uint4 v; unsigned short u[8]; } w;
    #pragma unroll
    for (int e = 0; e < 8; e++) w.u[e] = (e == e1) ? 0x3F80 : 0;
    ((uint4*)(ws + WSOFF_RF))[q2] = w.v;
  }
}

// Main kernel, 512 threads, NO occupancy hints. 48 KB LDS -> 3 blocks/CU.
// HOMOGENEOUS grid: every block = 8 waves x 1 MLP tile + 3 f32x4/thread
// copy slice (sequential after the tile, so no live-range growth).
__global__ void k_main(
    const float* __restrict__ x, const int* __restrict__ pidx,
    const float* __restrict__ b2, const char* __restrict__ ws,
    float* __restrict__ out)
{
  __shared__ uint4 sB2[2048];   // 32 KB: W2 B-fragments [frag(kk*8+n)][lane]
  __shared__ uint4 sWR[1024];   // 16 KB: [0,512) W1 frags, [512,1024) R frags

  const int bid = blockIdx.x;
  const int tid = threadIdx.x;

  // ---- stage pre-packed fragments into LDS (6 x 16B per thread) ----
  const uint4* W2f = (const uint4*)(ws + WSOFF_W2F);
  const uint4* WRf = (const uint4*)(ws + WSOFF_W1F);  // W1+R contiguous, 1024
  #pragma unroll
  for (int i = 0; i < 4; i++) sB2[i*512 + tid] = W2f[i*512 + tid];
  sWR[tid] = WRf[tid];                   // W1 fragments
  sWR[512 + tid] = WRf[512 + tid];       // R fragments
  __syncthreads();

  const int lane = tid & 63;
  const int wv   = tid >> 6;
  const int r15  = lane & 15;
  const int g    = lane >> 4;
  const float* G1 = (const float*)ws;

  const bf16x8* B2f = (const bf16x8*)sB2;
  const bf16x8* B1f = (const bf16x8*)sWR;          // frags 0..7
  const bf16x8* Rf  = (const bf16x8*)(sWR + 512);  // frags 0..7

  const int tl   = bid*8 + wv;             // tile index (one per wave)
  const int row0 = tl*16;

  // This lane's batch row within the tile is r15 (transposed layout).
  const int idxA = pidx[row0 + r15];

  // x row: A/B fragment source (cols 8g..8g+7)
  const float* ap = x + idxA*NF + 8*g;
  float4 a0 = *(const float4*)ap;
  float4 a1 = *(const float4*)(ap + 4);

  // GEMM1 acc init: G1 row (bias + global half folded in), float4 loads
  const int g1r = idxA & (BATCH-1);
  f32x4 acc1[8];
  #pragma unroll
  for (int n = 0; n < 8; n++)
    acc1[n] = *(const f32x4*)(G1 + g1r*DOUT + 16*n + 4*g);

  // convert A-fragment
  union { bf16x8 v; __hip_bfloat162 h[4]; } af;
  af.h[0] = __float22bfloat162_rn(make_float2(a0.x, a0.y));
  af.h[1] = __float22bfloat162_rn(make_float2(a0.z, a0.w));
  af.h[2] = __float22bfloat162_rn(make_float2(a1.x, a1.y));
  af.h[3] = __float22bfloat162_rn(make_float2(a1.z, a1.w));

  // GEMM1 (transposed): acc1[n][r] = h1[row_r15][16n+4g+r]
  #pragma unroll
  for (int n = 0; n < 8; n++)
    acc1[n] = __builtin_amdgcn_mfma_f32_16x16x32_bf16(B1f[n*64 + lane], af.v, acc1[n], 0, 0, 0);

  // leaky-relu + pack to bf16 pairs, all in registers
  __hip_bfloat162 pa[8][2];
  #pragma unroll
  for (int n = 0; n < 8; n++){
    float v0 = acc1[n][0], v1 = acc1[n][1], v2 = acc1[n][2], v3 = acc1[n][3];
    v0 = v0 > 0.f ? v0 : 0.01f*v0;
    v1 = v1 > 0.f ? v1 : 0.01f*v1;
    v2 = v2 > 0.f ? v2 : 0.01f*v2;
    v3 = v3 > 0.f ? v3 : 0.01f*v3;
    pa[n][0] = __float22bfloat162_rn(make_float2(v0, v1));
    pa[n][1] = __float22bfloat162_rn(make_float2(v2, v3));
  }

  // GEMM2: b2 folded into init, residual folded in via R-fragment MFMA.
  // A-operand for MFMA kk = {acc1[2kk], acc1[2kk+1]} packed — the sigma
  // permutation baked into the W2 fragments makes this exact (no LDS).
  f32x4 acc2[8];
  #pragma unroll
  for (int n = 0; n < 8; n++)
    acc2[n] = *(const f32x4*)(b2 + 16*n + 4*g);
  #pragma unroll
  for (int n = 0; n < 8; n++)
    acc2[n] = __builtin_amdgcn_mfma_f32_16x16x32_bf16(Rf[n*64 + lane], af.v, acc2[n], 0, 0, 0);
  #pragma unroll
  for (int kk = 0; kk < 4; kk++){
    union { bf16x8 v; __hip_bfloat162 h[4]; } a2;
    a2.h[0] = pa[2*kk][0];   a2.h[1] = pa[2*kk][1];
    a2.h[2] = pa[2*kk+1][0]; a2.h[3] = pa[2*kk+1][1];
    #pragma unroll
    for (int n = 0; n < 8; n++)
      acc2[n] = __builtin_amdgcn_mfma_f32_16x16x32_bf16(B2f[(kk*8 + n)*64 + lane], a2.v, acc2[n], 0, 0, 0);
  }

  // epilogue: pure f32x4 stores to children layout (no trailing loads)
  const int p  = row0 >> 11;               // parent (tiles never cross parents)
  const int b0 = row0 & (BATCH-1);
  const int orow = CHBASE + ((p*NBR)*BATCH + b0 + r15)*NF;
  #pragma unroll
  for (int n = 0; n < 8; n++){
    int c0 = 16*n + 4*g;                   // first of 4 consecutive output cols
    int br = c0 >> 5, fc0 = c0 & 31;
    *(f32x4*)(out + orow + br*(BATCH*NF) + fc0) = acc2[n];
  }

  // ---- copy slice: out[0:NROWSX*NF] = x, 3 f32x4 per thread ----
  // 3 * NMLP * 512 == CPN4 exactly; uniform work across all blocks.
  const f32x4* src4 = (const f32x4*)x;
  f32x4* dst4 = (f32x4*)out;
  #pragma unroll
  for (int i = 0; i < 3; i++){
    int idx = (i*NMLP + bid)*512 + tid;
    dst4[idx] = src4[idx];
  }
}

extern "C" void kernel_launch(void* const* d_in, const int* in_sizes, int n_in,
                              void* d_out, int out_size, void* d_ws, size_t ws_size,
                              hipStream_t stream){
  const float* x   = (const float*)d_in[0];
  const float* gf  = (const float*)d_in[1];
  const int*   pidx= (const int*)d_in[2];
  const float* W1  = (const float*)d_in[3];
  const float* b1  = (const float*)d_in[4];
  const float* W2  = (const float*)d_in[5];
  const float* b2  = (const float*)d_in[6];
  float* out = (float*)d_out;
  char* ws   = (char*)d_ws;               // 1MB G1 + 48KB packed fragments

  k_prep<<<140, 256, 0, stream>>>(gf, W1, b1, W2, ws);
  k_main<<<NMLP, 512, 0, stream>>>(x, pidx, b2, ws, out);
}